// Round 13
// baseline (23.032 us; speedup 1.0000x reference)
//
#include <hip/hip_runtime.h>

#define NSEQ 4096
#define DIM  256
#define WIN  128
#define BATCH 4

typedef __bf16 bf16x8 __attribute__((ext_vector_type(8)));
typedef float  f32x4  __attribute__((ext_vector_type(4)));
typedef int    v2i    __attribute__((ext_vector_type(2)));
typedef int    v4i    __attribute__((ext_vector_type(4)));

// subtiled layout: element (j,d) of a 32x256 tile at
// ((j>>2)*16 + (d>>4))*64 + (j&3)*16 + (d&15)  halfwords. (verified r2-r12)
__device__ __forceinline__ int sub_off(int j, int d) {
    return (((j >> 2) * 16 + (d >> 4)) << 6) + ((j & 3) << 4) + (d & 15);
}

__device__ __forceinline__ unsigned short f2bf(float f) {
    unsigned u = __builtin_bit_cast(unsigned, f);
    u += 0x7fffu + ((u >> 16) & 1u);   // RNE
    return (unsigned short)(u >> 16);
}

// HW packed f32->bf16 (RNE)
__device__ __forceinline__ unsigned pk2bf(float lo, float hi) {
    unsigned r;
    asm("v_cvt_pk_bf16_f32 %0, %1, %2" : "=v"(r) : "v"(lo), "v"(hi));
    return r;
}

// async global->LDS DMA, 16B per lane (dest = wave-uniform base + lane*16)
__device__ __forceinline__ void gload16(const void* g, void* l) {
    __builtin_amdgcn_global_load_lds(
        (const __attribute__((address_space(1))) unsigned int*)g,
        (__attribute__((address_space(3))) unsigned int*)l, 16, 0, 0);
}

// ---- pre-pass: f32 -> bf16 subtiled tiles in ws (r3-verified structure) ----
__global__ __launch_bounds__(256)
void cvt_kernel(const float* __restrict__ val, unsigned short* __restrict__ wsA) {
    __shared__ unsigned short A_l[8192];
    const int tile = blockIdx.x;                    // global tile id
    const float* src = val + ((size_t)tile << 13);  // *32*256
    const int t = threadIdx.x;
    const int j = t >> 3;
    const int dbase = (t & 7) << 2;

    #pragma unroll
    for (int p = 0; p < 8; ++p) {
        const int d = dbase + (p << 5);
        float4 v = *reinterpret_cast<const float4*>(src + j * 256 + d);
        uint2 u;
        u.x = pk2bf(v.x, v.y);
        u.y = pk2bf(v.z, v.w);
        *reinterpret_cast<uint2*>(&A_l[sub_off(j, d)]) = u;
    }
    __syncthreads();
    unsigned short* dstA = wsA + ((size_t)tile << 13);
    #pragma unroll
    for (int i = 0; i < 4; ++i) {
        uint4 x = *reinterpret_cast<const uint4*>(&A_l[(i << 11) + (t << 3)]);
        *reinterpret_cast<uint4*>(dstA + (i << 11) + (t << 3)) = x;
    }
}

// ---- main kernel: r10 structure, staging via global_load_lds ----
__global__ __launch_bounds__(256, 3)
void sp_kernel(const unsigned short* __restrict__ wsA,
               const float* __restrict__ state,
               float* __restrict__ out) {
    __shared__ __align__(128) unsigned short vbuf[2][8192];  // 32 KB double buffer
    __shared__ __align__(128) unsigned short E_s[32 * 56];   // 3.5 KB
    __shared__ float ds_part[4][16];

    // XCD-aware bijective swizzle (512 = 8*64)
    const int bx  = blockIdx.x;
    const int lbx = ((bx & 7) << 6) + (bx >> 3);
    const int b      = lbx >> 7;
    const int tile_i = lbx & 127;
    const int r0     = tile_i << 5;

    const int t   = threadIdx.x;
    const int w   = t >> 6;
    const int l   = t & 63;
    const int l15 = l & 15;
    const int l4  = l >> 4;
    const int mt  = w >> 1;            // score row-tile (0..1)
    const int jt  = w & 1;             // score col-tile (0..1)

    const float* stb  = state + ((size_t)b * NSEQ);
    float* out_state  = out + ((size_t)b * NSEQ);
    float* out_val    = out + (size_t)BATCH * NSEQ + ((size_t)b * NSEQ) * DIM;

    // ---- prologue: DMA tile_i into vbuf[0] (byte-identical image to wsA tile) ----
    {
        const char* g = (const char*)wsA + (((size_t)((b << 7) + tile_i)) << 14);
        #pragma unroll
        for (int k = 0; k < 4; ++k) {
            const int off = ((w << 2) + k) << 10;   // 1 KB chunk per wave-call
            gload16(g + off + (l << 4), ((char*)&vbuf[0][0]) + off);
        }
    }
    __syncthreads();   // vmcnt drain completes the DMA

    // ---- A-fragments (Vi rows), registers for whole loop ----
    const int il = (mt << 4) + l15;
    const int jl = (jt << 4) + l15;
    bf16x8 af[8];
    #pragma unroll
    for (int ks = 0; ks < 8; ++ks)
        af[ks] = *reinterpret_cast<const bf16x8*>(&vbuf[0][sub_off(il, (l4 << 3) + (ks << 5))]);

    const int tj0   = (tile_i >= 4) ? (tile_i - 4) : 0;
    const int ntile = tile_i - tj0 + 1;

    float dsacc[4] = {0.f, 0.f, 0.f, 0.f};
    f32x4 accpv[2][4];
    #pragma unroll
    for (int m2 = 0; m2 < 2; ++m2)
        #pragma unroll
        for (int tt = 0; tt < 4; ++tt)
            accpv[m2][tt] = (f32x4){0.f, 0.f, 0.f, 0.f};

    int p = 0;
    for (int q = 0; q < ntile; ++q) {
        const int ti = tile_i - q;
        const bool havenext = (q + 1 < ntile);
        const unsigned short* bp = &vbuf[p][0];
        unsigned short* bn = &vbuf[1 - p][0];

        // ---- fire-and-forget: DMA next tile into bn (completes at barrier 1) ----
        if (havenext) {
            const char* g = (const char*)wsA + (((size_t)((b << 7) + ti - 1)) << 14);
            #pragma unroll
            for (int k = 0; k < 4; ++k) {
                const int off = ((w << 2) + k) << 10;
                gload16(g + off + (l << 4), ((char*)bn) + off);
            }
        }

        const int jg = (ti << 5) + jl;
        const float stv = stb[jg];

        // ---- scores: S(16x16 per wave) = Vi x Vj^T, K=256 ----
        bf16x8 sb[8];
        #pragma unroll
        for (int ks = 0; ks < 8; ++ks)
            sb[ks] = *reinterpret_cast<const bf16x8*>(&bp[sub_off(jl, (l4 << 3) + (ks << 5))]);
        f32x4 acc = (f32x4){0.f, 0.f, 0.f, 0.f};
        __builtin_amdgcn_s_setprio(1);
        #pragma unroll
        for (int ks = 0; ks < 8; ++ks)
            acc = __builtin_amdgcn_mfma_f32_16x16x32_bf16(af[ks], sb[ks], acc, 0, 0, 0);
        __builtin_amdgcn_s_setprio(0);

        // ---- edges: scale, softsign (fast rcp), mask; dsacc; E write ----
        const int ib = r0 + (mt << 4) + (l4 << 2);
        #pragma unroll
        for (int r = 0; r < 4; ++r) {
            float s = acc[r] * 0.0625f;      // / sqrt(256)
            float e = s * __builtin_amdgcn_rcpf(1.0f + fabsf(s));
            const int ig = ib + r;
            if (jg > ig || jg < ig - WIN) e = 0.0f;
            dsacc[r] += e * stv;
            E_s[((mt << 4) + (l4 << 2) + r) * 56 + (jt << 4) + l15] = f2bf(e);
        }
        __syncthreads();   // barrier 1: E visible; staging DMA drained

        // ---- PV: E frags, batched tr_reads from bp, MFMA ----
        bf16x8 ef0 = *reinterpret_cast<const bf16x8*>(&E_s[l15 * 56 + (l4 << 3)]);
        bf16x8 ef1 = *reinterpret_cast<const bf16x8*>(&E_s[(16 + l15) * 56 + (l4 << 3)]);
        const unsigned lds_base = (unsigned)(size_t)bp;
        v2i tr[8];
        #pragma unroll
        for (int tt = 0; tt < 4; ++tt) {
            const int nt = (w << 2) + tt;
            unsigned a0 = lds_base + (unsigned)((((l4 << 5) + nt) << 7) + (l15 << 3));
            asm volatile("ds_read_b64_tr_b16 %0, %1" : "=v"(tr[2 * tt]) : "v"(a0) : "memory");
            asm volatile("ds_read_b64_tr_b16 %0, %1 offset:2048" : "=v"(tr[2 * tt + 1]) : "v"(a0) : "memory");
        }
        asm volatile("s_waitcnt lgkmcnt(0)" ::: "memory");
        __builtin_amdgcn_sched_barrier(0);
        __builtin_amdgcn_s_setprio(1);
        #pragma unroll
        for (int tt = 0; tt < 4; ++tt) {
            v4i tmp;
            tmp.x = tr[2 * tt].x;     tmp.y = tr[2 * tt].y;
            tmp.z = tr[2 * tt + 1].x; tmp.w = tr[2 * tt + 1].y;
            bf16x8 bfr = __builtin_bit_cast(bf16x8, tmp);
            accpv[0][tt] = __builtin_amdgcn_mfma_f32_16x16x32_bf16(ef0, bfr, accpv[0][tt], 0, 0, 0);
            accpv[1][tt] = __builtin_amdgcn_mfma_f32_16x16x32_bf16(ef1, bfr, accpv[1][tt], 0, 0, 0);
        }
        __builtin_amdgcn_s_setprio(0);
        if (havenext) __syncthreads();   // barrier 2: bp reads done before its re-stage
        p ^= 1;
    }

    // ---- delta_state: shuffle-reduce 16 j-lanes, combine jt-halves via LDS ----
    #pragma unroll
    for (int m = 1; m <= 8; m <<= 1) {
        #pragma unroll
        for (int r = 0; r < 4; ++r)
            dsacc[r] += __shfl_xor(dsacc[r], m, 64);
    }
    if (l15 == 0) {
        #pragma unroll
        for (int r = 0; r < 4; ++r)
            ds_part[w][(l4 << 2) + r] = dsacc[r];
    }
    __syncthreads();
    if (t < 32) {
        const int m2 = t >> 4;
        out_state[r0 + t] = ds_part[(m2 << 1)][t & 15] + ds_part[(m2 << 1) + 1][t & 15];
    }

    // ---- delta_val epilogue: C layout col=lane&15, row=(lane>>4)*4+r (verified) ----
    #pragma unroll
    for (int m2 = 0; m2 < 2; ++m2) {
        #pragma unroll
        for (int tt = 0; tt < 4; ++tt) {
            const int d = (w << 6) + (tt << 4) + l15;
            #pragma unroll
            for (int r = 0; r < 4; ++r) {
                const int ig = r0 + (m2 << 4) + (l4 << 2) + r;
                out_val[(size_t)ig * DIM + d] = accpv[m2][tt][r];
            }
        }
    }
}

extern "C" void kernel_launch(void* const* d_in, const int* in_sizes, int n_in,
                              void* d_out, int out_size, void* d_ws, size_t ws_size,
                              hipStream_t stream) {
    const float* val   = (const float*)d_in[0];
    const float* state = (const float*)d_in[1];
    float* out = (float*)d_out;
    unsigned short* wsA = (unsigned short*)d_ws;   // 8.4 MB (ws >= 16.8 MB per r3)

    cvt_kernel<<<dim3(BATCH * 128), dim3(256), 0, stream>>>(val, wsA);
    sp_kernel<<<dim3(BATCH * 128), dim3(256), 0, stream>>>(wsA, state, out);
}

// Round 14
// 21.013 us; speedup vs baseline: 1.0961x; 1.0961x over previous
//
#include <hip/hip_runtime.h>

#define NSEQ 4096
#define DIM  256
#define WIN  128
#define BATCH 4

typedef __bf16 bf16x8 __attribute__((ext_vector_type(8)));
typedef float  f32x4  __attribute__((ext_vector_type(4)));
typedef int    v2i    __attribute__((ext_vector_type(2)));
typedef int    v4i    __attribute__((ext_vector_type(4)));

// subtiled layout: element (j,d) of a [rows]x256 tile at
// ((j>>2)*16 + (d>>4))*64 + (j&3)*16 + (d&15)  halfwords. (verified r2-r13)
__device__ __forceinline__ int sub_off(int j, int d) {
    return (((j >> 2) * 16 + (d >> 4)) << 6) + ((j & 3) << 4) + (d & 15);
}

__device__ __forceinline__ unsigned short f2bf(float f) {
    unsigned u = __builtin_bit_cast(unsigned, f);
    u += 0x7fffu + ((u >> 16) & 1u);   // RNE
    return (unsigned short)(u >> 16);
}

// HW packed f32->bf16 (RNE)
__device__ __forceinline__ unsigned pk2bf(float lo, float hi) {
    unsigned r;
    asm("v_cvt_pk_bf16_f32 %0, %1, %2" : "=v"(r) : "v"(lo), "v"(hi));
    return r;
}

#define ESTR 72   // E row stride in halfwords (144B -> 2-way bank alias, free)

__global__ __launch_bounds__(256, 2)
void sp_kernel(const float* __restrict__ val,
               const float* __restrict__ state,
               float* __restrict__ out) {
    __shared__ __align__(128) unsigned short vbuf[2][16384]; // 64 KB: 2 x (64x256 bf16)
    __shared__ __align__(128) unsigned short E_s[32 * ESTR]; // 4.6 KB
    __shared__ float ds_part[4][16];

    // XCD-aware bijective swizzle (512 = 8*64)
    const int bx  = blockIdx.x;
    const int lbx = ((bx & 7) << 6) + (bx >> 3);
    const int b      = lbx >> 7;
    const int tile_i = lbx & 127;
    const int r0     = tile_i << 5;    // BR = 32 output rows

    const int t   = threadIdx.x;
    const int w   = t >> 6;
    const int l   = t & 63;
    const int l15 = l & 15;
    const int l4  = l >> 4;
    const int mt  = w >> 1;            // i-half (0..1)
    const int jt  = w & 1;             // j-half of 64 (0..1)

    const float* valb = val + ((size_t)b * NSEQ) * DIM;
    const float* stb  = state + ((size_t)b * NSEQ);
    float* out_state  = out + ((size_t)b * NSEQ);
    float* out_val    = out + (size_t)BATCH * NSEQ + ((size_t)b * NSEQ) * DIM;

    // ---- af: Vi row fragments straight from global f32 (once) ----
    const int il = (mt << 4) + l15;
    bf16x8 af[8];
    {
        const float* rp = valb + (size_t)(r0 + il) * DIM + (l4 << 3);
        #pragma unroll
        for (int ks = 0; ks < 8; ++ks) {
            float4 u0 = *reinterpret_cast<const float4*>(rp + (ks << 5));
            float4 u1 = *reinterpret_cast<const float4*>(rp + (ks << 5) + 4);
            v4i pw;
            pw.x = pk2bf(u0.x, u0.y);
            pw.y = pk2bf(u0.z, u0.w);
            pw.z = pk2bf(u1.x, u1.y);
            pw.w = pk2bf(u1.z, u1.w);
            af[ks] = __builtin_bit_cast(bf16x8, pw);
        }
    }

    // ---- j-block range (64-wide, aligned) ----
    const int jb0   = (r0 >= WIN) ? ((r0 - WIN) & ~63) : 0;
    const int niter = (((r0 + 95) & ~63) - jb0) >> 6;   // 1..3

    // staging pattern: r2-verified pattern tiled 4x4 (64 rows x 256 cols)
    const int sj = (w << 2) + l4;
    const int sd = l15 << 2;

    // ---- prologue: stage first j-block into vbuf[0] ----
    {
        const float* src = valb + (size_t)jb0 * DIM;
        #pragma unroll
        for (int a = 0; a < 4; ++a)
            #pragma unroll
            for (int c = 0; c < 4; ++c) {
                const int jl = sj + (a << 4);
                const int d0 = sd + (c << 6);
                float4 v = *reinterpret_cast<const float4*>(src + jl * DIM + d0);
                uint2 u;
                u.x = pk2bf(v.x, v.y);
                u.y = pk2bf(v.z, v.w);
                *reinterpret_cast<uint2*>(&vbuf[0][sub_off(jl, d0)]) = u;
            }
    }
    __syncthreads();

    float dsacc[4] = {0.f, 0.f, 0.f, 0.f};
    f32x4 accpv[2][4];
    #pragma unroll
    for (int m2 = 0; m2 < 2; ++m2)
        #pragma unroll
        for (int tt = 0; tt < 4; ++tt)
            accpv[m2][tt] = (f32x4){0.f, 0.f, 0.f, 0.f};

    for (int q = 0; q < niter; ++q) {
        const int jb = jb0 + (q << 6);
        const bool havenext = (q + 1 < niter);
        const unsigned short* bp = &vbuf[q & 1][0];
        unsigned short* bn = &vbuf[(q + 1) & 1][0];

        // ---- scores: wave quadrant rows [mt*16,+16) x cols [jt*32,+32), K=256 ----
        // two independent acc chains (nn = 0,1)
        f32x4 acc0 = (f32x4){0.f, 0.f, 0.f, 0.f};
        f32x4 acc1 = (f32x4){0.f, 0.f, 0.f, 0.f};
        {
            const int jc0 = (jt << 5) + l15;
            const int jc1 = jc0 + 16;
            #pragma unroll
            for (int ks = 0; ks < 8; ++ks) {
                const int k = (l4 << 3) + (ks << 5);
                bf16x8 s0 = *reinterpret_cast<const bf16x8*>(&bp[sub_off(jc0, k)]);
                bf16x8 s1 = *reinterpret_cast<const bf16x8*>(&bp[sub_off(jc1, k)]);
                acc0 = __builtin_amdgcn_mfma_f32_16x16x32_bf16(af[ks], s0, acc0, 0, 0, 0);
                acc1 = __builtin_amdgcn_mfma_f32_16x16x32_bf16(af[ks], s1, acc1, 0, 0, 0);
            }
        }

        // ---- edges: scale, softsign, mask; dsacc; E write ----
        {
            const int jg0 = jb + (jt << 5) + l15;
            const int jg1 = jg0 + 16;
            const float stv0 = stb[jg0];
            const float stv1 = stb[jg1];
            const int ib = r0 + (mt << 4) + (l4 << 2);
            #pragma unroll
            for (int r = 0; r < 4; ++r) {
                const int ig = ib + r;
                const int irow = (mt << 4) + (l4 << 2) + r;
                float s0 = acc0[r] * 0.0625f;
                float e0 = s0 * __builtin_amdgcn_rcpf(1.0f + fabsf(s0));
                if (jg0 > ig || jg0 < ig - WIN) e0 = 0.0f;
                float s1 = acc1[r] * 0.0625f;
                float e1 = s1 * __builtin_amdgcn_rcpf(1.0f + fabsf(s1));
                if (jg1 > ig || jg1 < ig - WIN) e1 = 0.0f;
                dsacc[r] += e0 * stv0 + e1 * stv1;
                E_s[irow * ESTR + (jt << 5) + l15]      = f2bf(e0);
                E_s[irow * ESTR + (jt << 5) + 16 + l15] = f2bf(e1);
            }
        }

        // ---- stage next j-block inline ----
        if (havenext) {
            const float* src = valb + (size_t)(jb + 64) * DIM;
            #pragma unroll
            for (int a = 0; a < 4; ++a)
                #pragma unroll
                for (int c = 0; c < 4; ++c) {
                    const int jl = sj + (a << 4);
                    const int d0 = sd + (c << 6);
                    float4 v = *reinterpret_cast<const float4*>(src + jl * DIM + d0);
                    uint2 u;
                    u.x = pk2bf(v.x, v.y);
                    u.y = pk2bf(v.z, v.w);
                    *reinterpret_cast<uint2*>(&bn[sub_off(jl, d0)]) = u;
                }
        }
        __syncthreads();   // barrier 1: E visible (+ next tile staged)

        // ---- PV: delta_val(32x256) += E(32x64) x Vj(64x256); wave owns d [64w,64w+64) ----
        #pragma unroll
        for (int kf = 0; kf < 2; ++kf) {
            bf16x8 ef0 = *reinterpret_cast<const bf16x8*>(&E_s[l15 * ESTR + (kf << 5) + (l4 << 3)]);
            bf16x8 ef1 = *reinterpret_cast<const bf16x8*>(&E_s[(16 + l15) * ESTR + (kf << 5) + (l4 << 3)]);
            const unsigned lds_base = (unsigned)(size_t)bp + (unsigned)(kf << 14);
            v2i tr[8];
            #pragma unroll
            for (int tt = 0; tt < 4; ++tt) {
                const int nt = (w << 2) + tt;
                unsigned a0 = lds_base + (unsigned)((l4 << 12) + (nt << 7) + (l15 << 3));
                asm volatile("ds_read_b64_tr_b16 %0, %1" : "=v"(tr[2 * tt]) : "v"(a0) : "memory");
                asm volatile("ds_read_b64_tr_b16 %0, %1 offset:2048" : "=v"(tr[2 * tt + 1]) : "v"(a0) : "memory");
            }
            asm volatile("s_waitcnt lgkmcnt(0)" ::: "memory");
            __builtin_amdgcn_sched_barrier(0);
            #pragma unroll
            for (int tt = 0; tt < 4; ++tt) {
                v4i tmp;
                tmp.x = tr[2 * tt].x;     tmp.y = tr[2 * tt].y;
                tmp.z = tr[2 * tt + 1].x; tmp.w = tr[2 * tt + 1].y;
                bf16x8 bfr = __builtin_bit_cast(bf16x8, tmp);
                accpv[0][tt] = __builtin_amdgcn_mfma_f32_16x16x32_bf16(ef0, bfr, accpv[0][tt], 0, 0, 0);
                accpv[1][tt] = __builtin_amdgcn_mfma_f32_16x16x32_bf16(ef1, bfr, accpv[1][tt], 0, 0, 0);
            }
        }
        if (havenext) __syncthreads();   // barrier 2: E/bp reads done before reuse
    }

    // ---- delta_state: shuffle-reduce 16 j-lanes, combine jt-halves via LDS ----
    #pragma unroll
    for (int m = 1; m <= 8; m <<= 1) {
        #pragma unroll
        for (int r = 0; r < 4; ++r)
            dsacc[r] += __shfl_xor(dsacc[r], m, 64);
    }
    if (l15 == 0) {
        #pragma unroll
        for (int r = 0; r < 4; ++r)
            ds_part[w][(l4 << 2) + r] = dsacc[r];
    }
    __syncthreads();
    if (t < 32) {
        const int m2 = t >> 4;
        out_state[r0 + t] = ds_part[(m2 << 1)][t & 15] + ds_part[(m2 << 1) + 1][t & 15];
    }

    // ---- delta_val epilogue: C layout col=lane&15, row=(lane>>4)*4+r (verified) ----
    #pragma unroll
    for (int m2 = 0; m2 < 2; ++m2) {
        #pragma unroll
        for (int tt = 0; tt < 4; ++tt) {
            const int d = (w << 6) + (tt << 4) + l15;
            #pragma unroll
            for (int r = 0; r < 4; ++r) {
                const int ig = r0 + (m2 << 4) + (l4 << 2) + r;
                out_val[(size_t)ig * DIM + d] = accpv[m2][tt][r];
            }
        }
    }
}

extern "C" void kernel_launch(void* const* d_in, const int* in_sizes, int n_in,
                              void* d_out, int out_size, void* d_ws, size_t ws_size,
                              hipStream_t stream) {
    const float* val   = (const float*)d_in[0];
    const float* state = (const float*)d_in[1];
    float* out = (float*)d_out;
    sp_kernel<<<dim3(BATCH * (NSEQ / 32)), dim3(256), 0, stream>>>(val, state, out);
}